// Round 1
// baseline (499.859 us; speedup 1.0000x reference)
//
#include <hip/hip_runtime.h>

// GAT encoder: N=50000 nodes, E=800000 edges, H=4 heads, C=64 dims.
//
// Pipeline (all on `stream`, graph-capture safe):
//   memset(scal+deg) -> precompute (fold att einsums to per-head scalars)
//   -> hist (degree histogram + edge_attr sum) -> scan (exclusive prefix)
//   -> scatter (counting-sort edges by dst as (src, edge_attr) pairs)
//   -> gat (one wave per dst node: online softmax + message accumulate in regs)

#define N_NODES 50000
#define N_EDGES 800000

// ---- workspace layout (bytes) ----
// scal float[32]  : [0..7]=ws(h,k) [8..15]=wd(h,k) [16..19]=we(h) [20]=sum(ea)
constexpr size_t OFF_SCAL = 0;
constexpr size_t OFF_DEG  = 128;                       // int[N]
constexpr size_t OFF_ROW  = 200192;                    // int[N+1]
constexpr size_t OFF_CUR  = 400448;                    // int[N]
constexpr size_t OFF_SORT = 600576;                    // int2[E]
constexpr size_t MEMSET_BYTES = OFF_DEG + N_NODES * sizeof(int);  // scal+deg

__global__ void precompute_kernel(const float* __restrict__ W,
                                  const float* __restrict__ att_src,
                                  const float* __restrict__ att_dst,
                                  const float* __restrict__ W_edge,
                                  const float* __restrict__ att_edge,
                                  float* __restrict__ scal) {
    int t = threadIdx.x;            // 0..255 = (h*64 + c)
    int h = t >> 6, lane = t & 63;
    float w0 = W[2 * t], w1 = W[2 * t + 1];
    float as = att_src[t], ad = att_dst[t];
    float ae = att_edge[t], wE = W_edge[t];
    float v0 = as * w0, v1 = as * w1, v2 = ad * w0, v3 = ad * w1, v4 = ae * wE;
    for (int off = 32; off; off >>= 1) {
        v0 += __shfl_down(v0, off, 64);
        v1 += __shfl_down(v1, off, 64);
        v2 += __shfl_down(v2, off, 64);
        v3 += __shfl_down(v3, off, 64);
        v4 += __shfl_down(v4, off, 64);
    }
    if (lane == 0) {
        scal[2 * h]     = v0;  scal[2 * h + 1] = v1;
        scal[8 + 2 * h] = v2;  scal[9 + 2 * h] = v3;
        scal[16 + h]    = v4;
    }
}

// E = 3125 * 256 exactly -> no tail guards.
__global__ void hist_kernel(const int* __restrict__ ei,
                            const float* __restrict__ ea,
                            int* __restrict__ deg, float* __restrict__ scal) {
    int e = blockIdx.x * 256 + threadIdx.x;
    int dst = ei[N_EDGES + e];
    atomicAdd(&deg[dst], 1);
    float v = ea[e];
    for (int off = 32; off; off >>= 1) v += __shfl_down(v, off, 64);
    if ((threadIdx.x & 63) == 0) atomicAdd(&scal[20], v);
}

__global__ __launch_bounds__(1024) void scan_kernel(const int* __restrict__ deg,
                                                    int* __restrict__ row_start,
                                                    int* __restrict__ cursor) {
    __shared__ int s[1024];
    int t = threadIdx.x;
    const int CH = (N_NODES + 1023) / 1024;   // 49
    int base = t * CH;
    int tot = 0;
    for (int i = 0; i < CH; ++i) {
        int idx = base + i;
        if (idx < N_NODES) tot += deg[idx];
    }
    s[t] = tot;
    __syncthreads();
    for (int off = 1; off < 1024; off <<= 1) {
        int v = (t >= off) ? s[t - off] : 0;
        __syncthreads();
        s[t] += v;
        __syncthreads();
    }
    int run = s[t] - tot;                     // exclusive prefix
    for (int i = 0; i < CH; ++i) {
        int idx = base + i;
        if (idx < N_NODES) {
            row_start[idx] = run;
            cursor[idx]    = run;
            run += deg[idx];
        }
    }
    if (t == 1023) row_start[N_NODES] = s[1023];
}

__global__ void scatter_kernel(const int* __restrict__ ei,
                               const float* __restrict__ ea,
                               int* __restrict__ cursor,
                               int2* __restrict__ sorted) {
    int e = blockIdx.x * 256 + threadIdx.x;
    int src = ei[e], dst = ei[N_EDGES + e];
    int pos = atomicAdd(&cursor[dst], 1);
    sorted[pos] = make_int2(src, __float_as_int(ea[e]));
}

// One wave per dst node. Lane j owns output channels 4j..4j+3 (head = j>>4).
__global__ __launch_bounds__(256) void gat_kernel(
        const float2* __restrict__ x2, const float4* __restrict__ W4,
        const float* __restrict__ scal, const int* __restrict__ row_start,
        const int2* __restrict__ sorted, const float4* __restrict__ bias4,
        float4* __restrict__ out4) {
    int lane = threadIdx.x & 63;
    int node = blockIdx.x * 4 + (threadIdx.x >> 6);
    if (node >= N_NODES) return;
    int h = lane >> 4;

    // W rows 4*lane..4*lane+3 (2 floats each) in registers
    float4 wa = W4[lane * 2];
    float4 wb = W4[lane * 2 + 1];
    float ws0 = scal[2 * h],     ws1 = scal[2 * h + 1];
    float wd0 = scal[8 + 2 * h], wd1 = scal[9 + 2 * h];
    float weh = scal[16 + h];
    float meanea = scal[20] * (1.0f / N_EDGES);

    float2 xd = x2[node];
    float adst = xd.x * wd0 + xd.y * wd1;

    // self loop (src = dst = node, ea = mean)
    float a = xd.x * ws0 + xd.y * ws1 + adst + meanea * weh;
    a = fmaxf(a, 0.2f * a);                 // leaky_relu(0.2)
    float ex = __expf(a);
    float denom = ex;
    float4 acc;
    acc.x = ex * (xd.x * wa.x + xd.y * wa.y);
    acc.y = ex * (xd.x * wa.z + xd.y * wa.w);
    acc.z = ex * (xd.x * wb.x + xd.y * wb.y);
    acc.w = ex * (xd.x * wb.z + xd.y * wb.w);

    int rs = row_start[node], re = row_start[node + 1];
    for (int e = rs; e < re; ++e) {
        int2 pr  = sorted[e];
        float eav = __int_as_float(pr.y);
        float2 xs = x2[pr.x];
        float al = xs.x * ws0 + xs.y * ws1 + adst + eav * weh;
        al = fmaxf(al, 0.2f * al);
        float exv = __expf(al);
        denom += exv;
        acc.x += exv * (xs.x * wa.x + xs.y * wa.y);
        acc.y += exv * (xs.x * wa.z + xs.y * wa.w);
        acc.z += exv * (xs.x * wb.x + xs.y * wb.y);
        acc.w += exv * (xs.x * wb.z + xs.y * wb.w);
    }

    float inv = 1.0f / denom;
    float4 b = bias4[lane];
    float4 o;
    o.x = acc.x * inv + b.x;
    o.y = acc.y * inv + b.y;
    o.z = acc.z * inv + b.z;
    o.w = acc.w * inv + b.w;
    out4[node * 64 + lane] = o;
}

extern "C" void kernel_launch(void* const* d_in, const int* in_sizes, int n_in,
                              void* d_out, int out_size, void* d_ws, size_t ws_size,
                              hipStream_t stream) {
    const float* x        = (const float*)d_in[0];
    const int*   ei       = (const int*)  d_in[1];
    const float* ea       = (const float*)d_in[2];
    const float* W        = (const float*)d_in[3];
    const float* att_src  = (const float*)d_in[4];
    const float* att_dst  = (const float*)d_in[5];
    const float* W_edge   = (const float*)d_in[6];
    const float* att_edge = (const float*)d_in[7];
    const float* bias     = (const float*)d_in[8];

    char* ws = (char*)d_ws;
    float* scal     = (float*)(ws + OFF_SCAL);
    int*   deg      = (int*)  (ws + OFF_DEG);
    int*   row_st   = (int*)  (ws + OFF_ROW);
    int*   cursor   = (int*)  (ws + OFF_CUR);
    int2*  sorted   = (int2*) (ws + OFF_SORT);

    hipMemsetAsync(ws, 0, MEMSET_BYTES, stream);
    precompute_kernel<<<1, 256, 0, stream>>>(W, att_src, att_dst, W_edge, att_edge, scal);
    hist_kernel<<<N_EDGES / 256, 256, 0, stream>>>(ei, ea, deg, scal);
    scan_kernel<<<1, 1024, 0, stream>>>(deg, row_st, cursor);
    scatter_kernel<<<N_EDGES / 256, 256, 0, stream>>>(ei, ea, cursor, sorted);
    gat_kernel<<<(N_NODES + 3) / 4, 256, 0, stream>>>(
        (const float2*)x, (const float4*)W, scal, row_st, sorted,
        (const float4*)bias, (float4*)d_out);
}

// Round 2
// 370.479 us; speedup vs baseline: 1.3492x; 1.3492x over previous
//
#include <hip/hip_runtime.h>

// GAT encoder: N=50000 nodes, E=800000 edges, H=4 heads, C=64 dims.
//
// Pipeline (all on `stream`, graph-capture safe):
//   memset(scal+deg) -> precompute (fold att einsums to per-head scalars)
//   -> easum (block partials of sum(edge_attr), NO same-address atomics)
//   -> hist (degree histogram, scattered int atomics only)
//   -> scan (reduce easum partials -> scal[20]; exclusive prefix of deg)
//   -> scatter (counting-sort edges by dst as (src, edge_attr) pairs)
//   -> gat (one wave per dst node: softmax + message accumulate in regs)
//
// R1 note: same-address float atomicAdd (1/wave, 12500 total) serialized at
// ~33 cyc/RMW = 170 us in hist. Replaced with 256 block partials + reduce.

#define N_NODES 50000
#define N_EDGES 800000

// ---- workspace layout (bytes) ----
// scal float[32]  : [0..7]=ws(h,k) [8..15]=wd(h,k) [16..19]=we(h) [20]=sum(ea)
constexpr size_t OFF_SCAL = 0;
constexpr size_t OFF_PART = 128;      // float[256]
constexpr size_t OFF_DEG  = 1152;     // int[N]
constexpr size_t OFF_ROW  = 201216;   // int[N+1]
constexpr size_t OFF_CUR  = 401280;   // int[N]
constexpr size_t OFF_SORT = 601344;   // int2[E] -> ends at 7001344
constexpr size_t MEMSET_BYTES = OFF_DEG + N_NODES * sizeof(int);

__global__ void precompute_kernel(const float* __restrict__ W,
                                  const float* __restrict__ att_src,
                                  const float* __restrict__ att_dst,
                                  const float* __restrict__ W_edge,
                                  const float* __restrict__ att_edge,
                                  float* __restrict__ scal) {
    int t = threadIdx.x;            // 0..255 = (h*64 + c)
    int h = t >> 6, lane = t & 63;
    float w0 = W[2 * t], w1 = W[2 * t + 1];
    float as = att_src[t], ad = att_dst[t];
    float ae = att_edge[t], wE = W_edge[t];
    float v0 = as * w0, v1 = as * w1, v2 = ad * w0, v3 = ad * w1, v4 = ae * wE;
    for (int off = 32; off; off >>= 1) {
        v0 += __shfl_down(v0, off, 64);
        v1 += __shfl_down(v1, off, 64);
        v2 += __shfl_down(v2, off, 64);
        v3 += __shfl_down(v3, off, 64);
        v4 += __shfl_down(v4, off, 64);
    }
    if (lane == 0) {
        scal[2 * h]     = v0;  scal[2 * h + 1] = v1;
        scal[8 + 2 * h] = v2;  scal[9 + 2 * h] = v3;
        scal[16 + h]    = v4;
    }
}

// 256 blocks x 256 threads, grid-stride; one partial per block, no atomics.
__global__ __launch_bounds__(256) void easum_kernel(const float* __restrict__ ea,
                                                    float* __restrict__ part) {
    __shared__ float sm[4];
    float s = 0.0f;
    for (int i = blockIdx.x * 256 + threadIdx.x; i < N_EDGES; i += 65536)
        s += ea[i];
    for (int off = 32; off; off >>= 1) s += __shfl_down(s, off, 64);
    if ((threadIdx.x & 63) == 0) sm[threadIdx.x >> 6] = s;
    __syncthreads();
    if (threadIdx.x == 0) part[blockIdx.x] = sm[0] + sm[1] + sm[2] + sm[3];
}

// E = 3125 * 256 exactly -> no tail guards. Scattered atomics only.
__global__ void hist_kernel(const int* __restrict__ ei,
                            int* __restrict__ deg) {
    int e = blockIdx.x * 256 + threadIdx.x;
    atomicAdd(&deg[ei[N_EDGES + e]], 1);
}

__global__ __launch_bounds__(1024) void scan_kernel(const int* __restrict__ deg,
                                                    const float* __restrict__ part,
                                                    float* __restrict__ scal,
                                                    int* __restrict__ row_start,
                                                    int* __restrict__ cursor) {
    __shared__ int s[1024];
    __shared__ float sf[256];
    int t = threadIdx.x;

    // reduce easum partials -> scal[20]
    if (t < 256) sf[t] = part[t];
    __syncthreads();
    if (t < 64) {
        float v = sf[t] + sf[t + 64] + sf[t + 128] + sf[t + 192];
        for (int off = 32; off; off >>= 1) v += __shfl_down(v, off, 64);
        if (t == 0) scal[20] = v;
    }

    const int CH = (N_NODES + 1023) / 1024;   // 49
    int base = t * CH;
    int tot = 0;
    for (int i = 0; i < CH; ++i) {
        int idx = base + i;
        if (idx < N_NODES) tot += deg[idx];
    }
    s[t] = tot;
    __syncthreads();
    for (int off = 1; off < 1024; off <<= 1) {
        int v = (t >= off) ? s[t - off] : 0;
        __syncthreads();
        s[t] += v;
        __syncthreads();
    }
    int run = s[t] - tot;                     // exclusive prefix
    for (int i = 0; i < CH; ++i) {
        int idx = base + i;
        if (idx < N_NODES) {
            row_start[idx] = run;
            cursor[idx]    = run;
            run += deg[idx];
        }
    }
    if (t == 1023) row_start[N_NODES] = s[1023];
}

__global__ void scatter_kernel(const int* __restrict__ ei,
                               const float* __restrict__ ea,
                               int* __restrict__ cursor,
                               int2* __restrict__ sorted) {
    int e = blockIdx.x * 256 + threadIdx.x;
    int src = ei[e], dst = ei[N_EDGES + e];
    int pos = atomicAdd(&cursor[dst], 1);
    sorted[pos] = make_int2(src, __float_as_int(ea[e]));
}

// One wave per dst node. Lane j owns output channels 4j..4j+3 (head = j>>4).
__global__ __launch_bounds__(256) void gat_kernel(
        const float2* __restrict__ x2, const float4* __restrict__ W4,
        const float* __restrict__ scal, const int* __restrict__ row_start,
        const int2* __restrict__ sorted, const float4* __restrict__ bias4,
        float4* __restrict__ out4) {
    int lane = threadIdx.x & 63;
    int node = blockIdx.x * 4 + (threadIdx.x >> 6);
    if (node >= N_NODES) return;
    int h = lane >> 4;

    // W rows 4*lane..4*lane+3 (2 floats each) in registers
    float4 wa = W4[lane * 2];
    float4 wb = W4[lane * 2 + 1];
    float ws0 = scal[2 * h],     ws1 = scal[2 * h + 1];
    float wd0 = scal[8 + 2 * h], wd1 = scal[9 + 2 * h];
    float weh = scal[16 + h];
    float meanea = scal[20] * (1.0f / N_EDGES);

    float2 xd = x2[node];
    float adst = xd.x * wd0 + xd.y * wd1;

    // self loop (src = dst = node, ea = mean)
    float a = xd.x * ws0 + xd.y * ws1 + adst + meanea * weh;
    a = fmaxf(a, 0.2f * a);                 // leaky_relu(0.2)
    float ex = __expf(a);
    float denom = ex;
    float4 acc;
    acc.x = ex * (xd.x * wa.x + xd.y * wa.y);
    acc.y = ex * (xd.x * wa.z + xd.y * wa.w);
    acc.z = ex * (xd.x * wb.x + xd.y * wb.y);
    acc.w = ex * (xd.x * wb.z + xd.y * wb.w);

    int rs = row_start[node], re = row_start[node + 1];
    for (int e = rs; e < re; ++e) {
        int2 pr  = sorted[e];
        float eav = __int_as_float(pr.y);
        float2 xs = x2[pr.x];
        float al = xs.x * ws0 + xs.y * ws1 + adst + eav * weh;
        al = fmaxf(al, 0.2f * al);
        float exv = __expf(al);
        denom += exv;
        acc.x += exv * (xs.x * wa.x + xs.y * wa.y);
        acc.y += exv * (xs.x * wa.z + xs.y * wa.w);
        acc.z += exv * (xs.x * wb.x + xs.y * wb.y);
        acc.w += exv * (xs.x * wb.z + xs.y * wb.w);
    }

    float inv = 1.0f / denom;
    float4 b = bias4[lane];
    float4 o;
    o.x = acc.x * inv + b.x;
    o.y = acc.y * inv + b.y;
    o.z = acc.z * inv + b.z;
    o.w = acc.w * inv + b.w;
    out4[node * 64 + lane] = o;
}

extern "C" void kernel_launch(void* const* d_in, const int* in_sizes, int n_in,
                              void* d_out, int out_size, void* d_ws, size_t ws_size,
                              hipStream_t stream) {
    const float* x        = (const float*)d_in[0];
    const int*   ei       = (const int*)  d_in[1];
    const float* ea       = (const float*)d_in[2];
    const float* W        = (const float*)d_in[3];
    const float* att_src  = (const float*)d_in[4];
    const float* att_dst  = (const float*)d_in[5];
    const float* W_edge   = (const float*)d_in[6];
    const float* att_edge = (const float*)d_in[7];
    const float* bias     = (const float*)d_in[8];

    char* ws = (char*)d_ws;
    float* scal     = (float*)(ws + OFF_SCAL);
    float* part     = (float*)(ws + OFF_PART);
    int*   deg      = (int*)  (ws + OFF_DEG);
    int*   row_st   = (int*)  (ws + OFF_ROW);
    int*   cursor   = (int*)  (ws + OFF_CUR);
    int2*  sorted   = (int2*) (ws + OFF_SORT);

    hipMemsetAsync(ws, 0, MEMSET_BYTES, stream);
    precompute_kernel<<<1, 256, 0, stream>>>(W, att_src, att_dst, W_edge, att_edge, scal);
    easum_kernel<<<256, 256, 0, stream>>>(ea, part);
    hist_kernel<<<N_EDGES / 256, 256, 0, stream>>>(ei, deg);
    scan_kernel<<<1, 1024, 0, stream>>>(deg, part, scal, row_st, cursor);
    scatter_kernel<<<N_EDGES / 256, 256, 0, stream>>>(ei, ea, cursor, sorted);
    gat_kernel<<<(N_NODES + 3) / 4, 256, 0, stream>>>(
        (const float2*)x, (const float4*)W, scal, row_st, sorted,
        (const float4*)bias, (float4*)d_out);
}

// Round 3
// 250.461 us; speedup vs baseline: 1.9958x; 1.4792x over previous
//
#include <hip/hip_runtime.h>

// GAT encoder: N=50000 nodes, E=800000 edges, H=4 heads, C=64 dims.
//
// Pipeline (all on `stream`, graph-capture safe):
//   memset(deg) -> precompute (fold att einsums to per-head scalars)
//   -> hist (degree histogram via scattered int atomics + per-block ea sums)
//   -> scan1/scan2/scan3 (3-phase parallel exclusive prefix sum of deg)
//   -> scatter (counting-sort edges by dst as (src, edge_attr) pairs)
//   -> gat (one wave per dst node: softmax + message accumulate in regs)
//
// R1: same-address float atomicAdd serialized ~33cyc/RMW = 170us -> partials.
// R2: single-block scan = 126us on one CU -> 3-phase grid-wide scan.

#define N_NODES 50000
#define N_EDGES 800000
#define HIST_BLOCKS (N_EDGES / 256)     // 3125
#define SCAN_BLOCKS 49                  // ceil(12500 int4 / 256)

// ---- workspace layout (bytes) ----
// scal float[32]: [0..7]=ws(h,k) [8..15]=wd(h,k) [16..19]=we(h) [20]=sum(ea)
constexpr size_t OFF_SCAL = 0;
constexpr size_t OFF_PART = 128;      // float[3125] ea block partials
constexpr size_t OFF_BSUM = 12672;    // int[64] scan block sums
constexpr size_t OFF_BOFF = 12928;    // int[64] scan block offsets
constexpr size_t OFF_DEG  = 13184;    // int[N]
constexpr size_t OFF_ROW  = 213184;   // int[N+1]
constexpr size_t OFF_CUR  = 413200;   // int[N]
constexpr size_t OFF_SORT = 613200;   // int2[E] -> ends at 7013200

__global__ void precompute_kernel(const float* __restrict__ W,
                                  const float* __restrict__ att_src,
                                  const float* __restrict__ att_dst,
                                  const float* __restrict__ W_edge,
                                  const float* __restrict__ att_edge,
                                  float* __restrict__ scal) {
    int t = threadIdx.x;            // 0..255 = (h*64 + c)
    int h = t >> 6, lane = t & 63;
    float w0 = W[2 * t], w1 = W[2 * t + 1];
    float as = att_src[t], ad = att_dst[t];
    float ae = att_edge[t], wE = W_edge[t];
    float v0 = as * w0, v1 = as * w1, v2 = ad * w0, v3 = ad * w1, v4 = ae * wE;
    for (int off = 32; off; off >>= 1) {
        v0 += __shfl_down(v0, off, 64);
        v1 += __shfl_down(v1, off, 64);
        v2 += __shfl_down(v2, off, 64);
        v3 += __shfl_down(v3, off, 64);
        v4 += __shfl_down(v4, off, 64);
    }
    if (lane == 0) {
        scal[2 * h]     = v0;  scal[2 * h + 1] = v1;
        scal[8 + 2 * h] = v2;  scal[9 + 2 * h] = v3;
        scal[16 + h]    = v4;
    }
}

// E = 3125 * 256 exactly. Scattered deg atomics + per-block ea partial sum.
__global__ __launch_bounds__(256) void hist_kernel(const int* __restrict__ ei,
                                                   const float* __restrict__ ea,
                                                   int* __restrict__ deg,
                                                   float* __restrict__ part) {
    __shared__ float sm[4];
    int e = blockIdx.x * 256 + threadIdx.x;
    atomicAdd(&deg[ei[N_EDGES + e]], 1);
    float v = ea[e];
    for (int off = 32; off; off >>= 1) v += __shfl_down(v, off, 64);
    if ((threadIdx.x & 63) == 0) sm[threadIdx.x >> 6] = v;
    __syncthreads();
    if (threadIdx.x == 0) part[blockIdx.x] = sm[0] + sm[1] + sm[2] + sm[3];
}

// Phase 1: per-block scan. Each thread owns an int4 of deg (coalesced).
__global__ __launch_bounds__(256) void scan1_kernel(const int4* __restrict__ deg4,
                                                    int4* __restrict__ row4,
                                                    int* __restrict__ bsum) {
    __shared__ int sm[4];
    int t = threadIdx.x, lane = t & 63, w = t >> 6;
    int gid = blockIdx.x * 256 + t;
    int4 d = make_int4(0, 0, 0, 0);
    if (gid < 12500) d = deg4[gid];
    int mysum = d.x + d.y + d.z + d.w;
    int s = mysum;
    for (int off = 1; off < 64; off <<= 1) {
        int v = __shfl_up(s, off, 64);
        if (lane >= off) s += v;
    }
    if (lane == 63) sm[w] = s;
    __syncthreads();
    int woff = 0;
    for (int i = 0; i < 4; ++i) if (i < w) woff += sm[i];
    int base = woff + s - mysum;          // block-local exclusive prefix
    if (gid < 12500) {
        int4 r;
        r.x = base;
        r.y = r.x + d.x;
        r.z = r.y + d.y;
        r.w = r.z + d.z;
        row4[gid] = r;
    }
    if (t == 0) bsum[blockIdx.x] = sm[0] + sm[1] + sm[2] + sm[3];
}

// Phase 2: scan 49 block sums; reduce ea partials -> scal[20]; row[N]=E.
__global__ __launch_bounds__(256) void scan2_kernel(const int* __restrict__ bsum,
                                                    const float* __restrict__ part,
                                                    int* __restrict__ boff,
                                                    int* __restrict__ row_start,
                                                    float* __restrict__ scal) {
    __shared__ float sf[4];
    int t = threadIdx.x, lane = t & 63;
    float v = 0.0f;
    for (int i = t; i < HIST_BLOCKS; i += 256) v += part[i];
    for (int off = 32; off; off >>= 1) v += __shfl_down(v, off, 64);
    if (lane == 0) sf[t >> 6] = v;
    __syncthreads();
    if (t == 0) scal[20] = sf[0] + sf[1] + sf[2] + sf[3];

    if (t < 64) {
        int s = (lane < SCAN_BLOCKS) ? bsum[lane] : 0;
        int own = s;
        for (int off = 1; off < 64; off <<= 1) {
            int x = __shfl_up(s, off, 64);
            if (lane >= off) s += x;
        }
        if (lane < SCAN_BLOCKS) boff[lane] = s - own;   // exclusive
        if (lane == SCAN_BLOCKS - 1) row_start[N_NODES] = s;
    }
}

// Phase 3: add block offsets; duplicate into cursor.
__global__ __launch_bounds__(256) void scan3_kernel(const int* __restrict__ boff,
                                                    int4* __restrict__ row4,
                                                    int4* __restrict__ cur4) {
    int gid = blockIdx.x * 256 + threadIdx.x;
    if (gid >= 12500) return;
    int o = boff[blockIdx.x];
    int4 r = row4[gid];
    r.x += o; r.y += o; r.z += o; r.w += o;
    row4[gid] = r;
    cur4[gid] = r;
}

__global__ __launch_bounds__(256) void scatter_kernel(const int* __restrict__ ei,
                                                      const float* __restrict__ ea,
                                                      int* __restrict__ cursor,
                                                      int2* __restrict__ sorted) {
    int e = blockIdx.x * 256 + threadIdx.x;
    int src = ei[e], dst = ei[N_EDGES + e];
    int pos = atomicAdd(&cursor[dst], 1);
    sorted[pos] = make_int2(src, __float_as_int(ea[e]));
}

// One wave per dst node. Lane j owns output channels 4j..4j+3 (head = j>>4).
__global__ __launch_bounds__(256) void gat_kernel(
        const float2* __restrict__ x2, const float4* __restrict__ W4,
        const float* __restrict__ scal, const int* __restrict__ row_start,
        const int2* __restrict__ sorted, const float4* __restrict__ bias4,
        float4* __restrict__ out4) {
    int lane = threadIdx.x & 63;
    int node = blockIdx.x * 4 + (threadIdx.x >> 6);
    if (node >= N_NODES) return;
    int h = lane >> 4;

    float4 wa = W4[lane * 2];
    float4 wb = W4[lane * 2 + 1];
    float ws0 = scal[2 * h],     ws1 = scal[2 * h + 1];
    float wd0 = scal[8 + 2 * h], wd1 = scal[9 + 2 * h];
    float weh = scal[16 + h];
    float meanea = scal[20] * (1.0f / N_EDGES);

    float2 xd = x2[node];
    float adst = xd.x * wd0 + xd.y * wd1;

    // self loop (src = dst = node, ea = mean)
    float a = xd.x * ws0 + xd.y * ws1 + adst + meanea * weh;
    a = fmaxf(a, 0.2f * a);                 // leaky_relu(0.2)
    float ex = __expf(a);
    float denom = ex;
    float4 acc;
    acc.x = ex * (xd.x * wa.x + xd.y * wa.y);
    acc.y = ex * (xd.x * wa.z + xd.y * wa.w);
    acc.z = ex * (xd.x * wb.x + xd.y * wb.y);
    acc.w = ex * (xd.x * wb.z + xd.y * wb.w);

    int rs = row_start[node], re = row_start[node + 1];
    for (int e = rs; e < re; ++e) {
        int2 pr  = sorted[e];
        float eav = __int_as_float(pr.y);
        float2 xs = x2[pr.x];
        float al = xs.x * ws0 + xs.y * ws1 + adst + eav * weh;
        al = fmaxf(al, 0.2f * al);
        float exv = __expf(al);
        denom += exv;
        acc.x += exv * (xs.x * wa.x + xs.y * wa.y);
        acc.y += exv * (xs.x * wa.z + xs.y * wa.w);
        acc.z += exv * (xs.x * wb.x + xs.y * wb.y);
        acc.w += exv * (xs.x * wb.z + xs.y * wb.w);
    }

    float inv = 1.0f / denom;
    float4 b = bias4[lane];
    float4 o;
    o.x = acc.x * inv + b.x;
    o.y = acc.y * inv + b.y;
    o.z = acc.z * inv + b.z;
    o.w = acc.w * inv + b.w;
    out4[node * 64 + lane] = o;
}

extern "C" void kernel_launch(void* const* d_in, const int* in_sizes, int n_in,
                              void* d_out, int out_size, void* d_ws, size_t ws_size,
                              hipStream_t stream) {
    const float* x        = (const float*)d_in[0];
    const int*   ei       = (const int*)  d_in[1];
    const float* ea       = (const float*)d_in[2];
    const float* W        = (const float*)d_in[3];
    const float* att_src  = (const float*)d_in[4];
    const float* att_dst  = (const float*)d_in[5];
    const float* W_edge   = (const float*)d_in[6];
    const float* att_edge = (const float*)d_in[7];
    const float* bias     = (const float*)d_in[8];

    char* ws = (char*)d_ws;
    float* scal   = (float*)(ws + OFF_SCAL);
    float* part   = (float*)(ws + OFF_PART);
    int*   bsum   = (int*)  (ws + OFF_BSUM);
    int*   boff   = (int*)  (ws + OFF_BOFF);
    int*   deg    = (int*)  (ws + OFF_DEG);
    int*   row_st = (int*)  (ws + OFF_ROW);
    int*   cursor = (int*)  (ws + OFF_CUR);
    int2*  sorted = (int2*) (ws + OFF_SORT);

    hipMemsetAsync(deg, 0, N_NODES * sizeof(int), stream);
    precompute_kernel<<<1, 256, 0, stream>>>(W, att_src, att_dst, W_edge, att_edge, scal);
    hist_kernel<<<HIST_BLOCKS, 256, 0, stream>>>(ei, ea, deg, part);
    scan1_kernel<<<SCAN_BLOCKS, 256, 0, stream>>>((const int4*)deg, (int4*)row_st, bsum);
    scan2_kernel<<<1, 256, 0, stream>>>(bsum, part, boff, row_st, scal);
    scan3_kernel<<<SCAN_BLOCKS, 256, 0, stream>>>(boff, (int4*)row_st, (int4*)cursor);
    scatter_kernel<<<HIST_BLOCKS, 256, 0, stream>>>(ei, ea, cursor, sorted);
    gat_kernel<<<(N_NODES + 3) / 4, 256, 0, stream>>>(
        (const float2*)x, (const float4*)W, scal, row_st, sorted,
        (const float4*)bias, (float4*)d_out);
}

// Round 4
// 160.645 us; speedup vs baseline: 3.1116x; 1.5591x over previous
//
#include <hip/hip_runtime.h>

// GAT encoder: N=50000 nodes, E=800000 edges, H=4 heads, C=64 dims.
//
// Pipeline (all on `stream`, graph-capture safe):
//   memset(deg) -> precompute (fold att einsums to per-head scalars)
//   -> hist (degree histogram; atomic return value = per-edge rank)
//   -> scan1/scan2/scan3 (3-phase parallel exclusive prefix sum of deg)
//   -> scatter (counting-sort edges by dst; atomic-free if rank path fits ws)
//   -> gat (16 lanes/node, edges across lanes, 12-scalar factored reduction)
//
// R1: same-address float atomicAdd serialized ~33cyc/RMW = 170us -> partials.
// R2: single-block scan = 126us on one CU -> 3-phase grid-wide scan.
// R3: gat replicated per-edge work across 64 lanes + serial edge loop (78us,
//     VALU-bound). Factor msg accumulation into per-head (Sx,Sy,D); edges
//     parallel across 16 lanes/node; channel work -> coalesced epilogue.

#define N_NODES 50000
#define N_EDGES 800000
#define HIST_BLOCKS (N_EDGES / 256)     // 3125
#define SCAN_BLOCKS 49                  // ceil(12500 int4 / 256)

// ---- workspace layout (bytes) ----
// scal float[32]: [0..7]=ws(h,k) [8..15]=wd(h,k) [16..19]=we(h) [20]=sum(ea)
constexpr size_t OFF_SCAL = 0;
constexpr size_t OFF_PART = 128;       // float[3125]
constexpr size_t OFF_BSUM = 12800;     // int[64]
constexpr size_t OFF_BOFF = 13056;     // int[64]
constexpr size_t OFF_DEG  = 13312;     // int[N]        -> 213312
constexpr size_t OFF_ROW  = 213312;    // int[N+1]      -> 413316 (pad)
constexpr size_t OFF_CUR  = 413328;    // int[N]  (fallback path only)
constexpr size_t OFF_SORT = 613328;    // int2[E]       -> 7013328
constexpr size_t OFF_RANK = 7013328;   // int[E] (rank path) -> 10213328
constexpr size_t NEED_RANK = OFF_RANK + (size_t)N_EDGES * sizeof(int);

__global__ void precompute_kernel(const float* __restrict__ W,
                                  const float* __restrict__ att_src,
                                  const float* __restrict__ att_dst,
                                  const float* __restrict__ W_edge,
                                  const float* __restrict__ att_edge,
                                  float* __restrict__ scal) {
    int t = threadIdx.x;            // 0..255 = (h*64 + c)
    int h = t >> 6, lane = t & 63;
    float w0 = W[2 * t], w1 = W[2 * t + 1];
    float as = att_src[t], ad = att_dst[t];
    float ae = att_edge[t], wE = W_edge[t];
    float v0 = as * w0, v1 = as * w1, v2 = ad * w0, v3 = ad * w1, v4 = ae * wE;
    for (int off = 32; off; off >>= 1) {
        v0 += __shfl_down(v0, off, 64);
        v1 += __shfl_down(v1, off, 64);
        v2 += __shfl_down(v2, off, 64);
        v3 += __shfl_down(v3, off, 64);
        v4 += __shfl_down(v4, off, 64);
    }
    if (lane == 0) {
        scal[2 * h]     = v0;  scal[2 * h + 1] = v1;
        scal[8 + 2 * h] = v2;  scal[9 + 2 * h] = v3;
        scal[16 + h]    = v4;
    }
}

// E = 3125 * 256 exactly. Rank path: atomic return value = within-dst rank.
__global__ __launch_bounds__(256) void hist_rank_kernel(const int* __restrict__ ei,
                                                        const float* __restrict__ ea,
                                                        int* __restrict__ deg,
                                                        int* __restrict__ rank,
                                                        float* __restrict__ part) {
    __shared__ float sm[4];
    int e = blockIdx.x * 256 + threadIdx.x;
    rank[e] = atomicAdd(&deg[ei[N_EDGES + e]], 1);
    float v = ea[e];
    for (int off = 32; off; off >>= 1) v += __shfl_down(v, off, 64);
    if ((threadIdx.x & 63) == 0) sm[threadIdx.x >> 6] = v;
    __syncthreads();
    if (threadIdx.x == 0) part[blockIdx.x] = sm[0] + sm[1] + sm[2] + sm[3];
}

__global__ __launch_bounds__(256) void hist_kernel(const int* __restrict__ ei,
                                                   const float* __restrict__ ea,
                                                   int* __restrict__ deg,
                                                   float* __restrict__ part) {
    __shared__ float sm[4];
    int e = blockIdx.x * 256 + threadIdx.x;
    atomicAdd(&deg[ei[N_EDGES + e]], 1);
    float v = ea[e];
    for (int off = 32; off; off >>= 1) v += __shfl_down(v, off, 64);
    if ((threadIdx.x & 63) == 0) sm[threadIdx.x >> 6] = v;
    __syncthreads();
    if (threadIdx.x == 0) part[blockIdx.x] = sm[0] + sm[1] + sm[2] + sm[3];
}

// Phase 1: per-block scan. Each thread owns an int4 of deg (coalesced).
__global__ __launch_bounds__(256) void scan1_kernel(const int4* __restrict__ deg4,
                                                    int4* __restrict__ row4,
                                                    int* __restrict__ bsum) {
    __shared__ int sm[4];
    int t = threadIdx.x, lane = t & 63, w = t >> 6;
    int gid = blockIdx.x * 256 + t;
    int4 d = make_int4(0, 0, 0, 0);
    if (gid < 12500) d = deg4[gid];
    int mysum = d.x + d.y + d.z + d.w;
    int s = mysum;
    for (int off = 1; off < 64; off <<= 1) {
        int v = __shfl_up(s, off, 64);
        if (lane >= off) s += v;
    }
    if (lane == 63) sm[w] = s;
    __syncthreads();
    int woff = 0;
    for (int i = 0; i < 4; ++i) if (i < w) woff += sm[i];
    int base = woff + s - mysum;          // block-local exclusive prefix
    if (gid < 12500) {
        int4 r;
        r.x = base;
        r.y = r.x + d.x;
        r.z = r.y + d.y;
        r.w = r.z + d.z;
        row4[gid] = r;
    }
    if (t == 0) bsum[blockIdx.x] = sm[0] + sm[1] + sm[2] + sm[3];
}

// Phase 2: scan 49 block sums; reduce ea partials -> scal[20]; row[N]=E.
__global__ __launch_bounds__(256) void scan2_kernel(const int* __restrict__ bsum,
                                                    const float* __restrict__ part,
                                                    int* __restrict__ boff,
                                                    int* __restrict__ row_start,
                                                    float* __restrict__ scal) {
    __shared__ float sf[4];
    int t = threadIdx.x, lane = t & 63;
    float v = 0.0f;
    for (int i = t; i < HIST_BLOCKS; i += 256) v += part[i];
    for (int off = 32; off; off >>= 1) v += __shfl_down(v, off, 64);
    if (lane == 0) sf[t >> 6] = v;
    __syncthreads();
    if (t == 0) scal[20] = sf[0] + sf[1] + sf[2] + sf[3];

    if (t < 64) {
        int s = (lane < SCAN_BLOCKS) ? bsum[lane] : 0;
        int own = s;
        for (int off = 1; off < 64; off <<= 1) {
            int x = __shfl_up(s, off, 64);
            if (lane >= off) s += x;
        }
        if (lane < SCAN_BLOCKS) boff[lane] = s - own;   // exclusive
        if (lane == SCAN_BLOCKS - 1) row_start[N_NODES] = s;
    }
}

// Phase 3: add block offsets (cur4 only used by fallback path).
__global__ __launch_bounds__(256) void scan3_kernel(const int* __restrict__ boff,
                                                    int4* __restrict__ row4,
                                                    int4* __restrict__ cur4) {
    int gid = blockIdx.x * 256 + threadIdx.x;
    if (gid >= 12500) return;
    int o = boff[blockIdx.x];
    int4 r = row4[gid];
    r.x += o; r.y += o; r.z += o; r.w += o;
    row4[gid] = r;
    if (cur4) cur4[gid] = r;
}

// Rank path: atomic-free scatter.
__global__ __launch_bounds__(256) void scatter_rank_kernel(
        const int* __restrict__ ei, const float* __restrict__ ea,
        const int* __restrict__ rank, const int* __restrict__ row_start,
        int2* __restrict__ sorted) {
    int e = blockIdx.x * 256 + threadIdx.x;
    int src = ei[e], dst = ei[N_EDGES + e];
    sorted[row_start[dst] + rank[e]] = make_int2(src, __float_as_int(ea[e]));
}

// Fallback path: cursor atomics.
__global__ __launch_bounds__(256) void scatter_kernel(const int* __restrict__ ei,
                                                      const float* __restrict__ ea,
                                                      int* __restrict__ cursor,
                                                      int2* __restrict__ sorted) {
    int e = blockIdx.x * 256 + threadIdx.x;
    int src = ei[e], dst = ei[N_EDGES + e];
    int pos = atomicAdd(&cursor[dst], 1);
    sorted[pos] = make_int2(src, __float_as_int(ea[e]));
}

// 16 lanes per node, 16 nodes per block, grid = 3125 (exact).
// Per edge (one lane each): 4 heads of (alpha, exp) -> accumulate
// (D, Sx, Sy) per head; butterfly-reduce within the 16-lane group;
// epilogue: lane sub writes float4s j = sub+16k (head k), coalesced.
__global__ __launch_bounds__(256) void gat_kernel(
        const float2* __restrict__ x2, const float4* __restrict__ W4,
        const float* __restrict__ scal, const int* __restrict__ row_start,
        const int2* __restrict__ sorted, const float4* __restrict__ bias4,
        float4* __restrict__ out4) {
    int t = threadIdx.x;
    int sub = t & 15;
    int node = blockIdx.x * 16 + (t >> 4);

    float ws0[4], ws1[4], wd0[4], wd1[4], we[4];
#pragma unroll
    for (int h = 0; h < 4; ++h) {
        ws0[h] = scal[2 * h];     ws1[h] = scal[2 * h + 1];
        wd0[h] = scal[8 + 2 * h]; wd1[h] = scal[9 + 2 * h];
        we[h]  = scal[16 + h];
    }
    float meanea = scal[20] * (1.0f / N_EDGES);

    float2 xd = x2[node];
    float adst[4];
#pragma unroll
    for (int h = 0; h < 4; ++h) adst[h] = xd.x * wd0[h] + xd.y * wd1[h];

    float D[4], Sx[4], Sy[4];
#pragma unroll
    for (int h = 0; h < 4; ++h) { D[h] = 0.0f; Sx[h] = 0.0f; Sy[h] = 0.0f; }

    if (sub == 0) {   // self loop (src = dst, ea = mean)
#pragma unroll
        for (int h = 0; h < 4; ++h) {
            float a = xd.x * ws0[h] + xd.y * ws1[h] + adst[h] + meanea * we[h];
            a = fmaxf(a, 0.2f * a);
            float ex = __expf(a);
            D[h] = ex; Sx[h] = ex * xd.x; Sy[h] = ex * xd.y;
        }
    }

    int rs = row_start[node], re = row_start[node + 1];
    for (int e = rs + sub; e < re; e += 16) {
        int2 pr = sorted[e];
        float2 xs = x2[pr.x];
        float eav = __int_as_float(pr.y);
#pragma unroll
        for (int h = 0; h < 4; ++h) {
            float a = xs.x * ws0[h] + xs.y * ws1[h] + adst[h] + eav * we[h];
            a = fmaxf(a, 0.2f * a);
            float ex = __expf(a);
            D[h] += ex; Sx[h] += ex * xs.x; Sy[h] += ex * xs.y;
        }
    }

#pragma unroll
    for (int m = 1; m < 16; m <<= 1) {
#pragma unroll
        for (int h = 0; h < 4; ++h) {
            D[h]  += __shfl_xor(D[h],  m, 16);
            Sx[h] += __shfl_xor(Sx[h], m, 16);
            Sy[h] += __shfl_xor(Sy[h], m, 16);
        }
    }

#pragma unroll
    for (int k = 0; k < 4; ++k) {
        int j = sub + 16 * k;
        float invD = 1.0f / D[k];
        float4 wa = W4[2 * j], wb = W4[2 * j + 1], b = bias4[j];
        float4 o;
        o.x = (wa.x * Sx[k] + wa.y * Sy[k]) * invD + b.x;
        o.y = (wa.z * Sx[k] + wa.w * Sy[k]) * invD + b.y;
        o.z = (wb.x * Sx[k] + wb.y * Sy[k]) * invD + b.z;
        o.w = (wb.z * Sx[k] + wb.w * Sy[k]) * invD + b.w;
        out4[node * 64 + j] = o;
    }
}

extern "C" void kernel_launch(void* const* d_in, const int* in_sizes, int n_in,
                              void* d_out, int out_size, void* d_ws, size_t ws_size,
                              hipStream_t stream) {
    const float* x        = (const float*)d_in[0];
    const int*   ei       = (const int*)  d_in[1];
    const float* ea       = (const float*)d_in[2];
    const float* W        = (const float*)d_in[3];
    const float* att_src  = (const float*)d_in[4];
    const float* att_dst  = (const float*)d_in[5];
    const float* W_edge   = (const float*)d_in[6];
    const float* att_edge = (const float*)d_in[7];
    const float* bias     = (const float*)d_in[8];

    char* ws = (char*)d_ws;
    float* scal   = (float*)(ws + OFF_SCAL);
    float* part   = (float*)(ws + OFF_PART);
    int*   bsum   = (int*)  (ws + OFF_BSUM);
    int*   boff   = (int*)  (ws + OFF_BOFF);
    int*   deg    = (int*)  (ws + OFF_DEG);
    int*   row_st = (int*)  (ws + OFF_ROW);
    int*   cursor = (int*)  (ws + OFF_CUR);
    int*   rank   = (int*)  (ws + OFF_RANK);
    int2*  sorted = (int2*) (ws + OFF_SORT);

    const bool use_rank = (ws_size >= NEED_RANK);   // ws_size is call-invariant

    hipMemsetAsync(deg, 0, N_NODES * sizeof(int), stream);
    precompute_kernel<<<1, 256, 0, stream>>>(W, att_src, att_dst, W_edge, att_edge, scal);
    if (use_rank)
        hist_rank_kernel<<<HIST_BLOCKS, 256, 0, stream>>>(ei, ea, deg, rank, part);
    else
        hist_kernel<<<HIST_BLOCKS, 256, 0, stream>>>(ei, ea, deg, part);
    scan1_kernel<<<SCAN_BLOCKS, 256, 0, stream>>>((const int4*)deg, (int4*)row_st, bsum);
    scan2_kernel<<<1, 256, 0, stream>>>(bsum, part, boff, row_st, scal);
    scan3_kernel<<<SCAN_BLOCKS, 256, 0, stream>>>(boff, (int4*)row_st,
                                                  use_rank ? (int4*)nullptr : (int4*)cursor);
    if (use_rank)
        scatter_rank_kernel<<<HIST_BLOCKS, 256, 0, stream>>>(ei, ea, rank, row_st, sorted);
    else
        scatter_kernel<<<HIST_BLOCKS, 256, 0, stream>>>(ei, ea, cursor, sorted);
    gat_kernel<<<N_NODES / 16, 256, 0, stream>>>(
        (const float2*)x, (const float4*)W, scal, row_st, sorted,
        (const float4*)bias, (float4*)d_out);
}